// Round 7
// baseline (604.944 us; speedup 1.0000x reference)
//
#include <hip/hip_runtime.h>

typedef unsigned short ushort_t;
typedef short bf16x8 __attribute__((ext_vector_type(8)));
typedef float f32x4 __attribute__((ext_vector_type(4)));

#define D_MODEL 2048
#define T_SEQ 2048
#define NB 2
#define NH 16
#define HD 128
#define M_ROWS 4096

__device__ __forceinline__ float b2f(unsigned short u) {
    return __uint_as_float(((unsigned)u) << 16);
}
__device__ __forceinline__ unsigned short f2b(float f) {
    unsigned u = __float_as_uint(f);
    u += 0x7fffu + ((u >> 16) & 1u);
    return (unsigned short)(u >> 16);
}

// async global->LDS, 16B per lane. lds base must be wave-uniform.
__device__ __forceinline__ void g2l16(const ushort_t* g, ushort_t* l) {
    __builtin_amdgcn_global_load_lds(
        (const __attribute__((address_space(1))) unsigned int*)g,
        (__attribute__((address_space(3))) unsigned int*)l, 16, 0, 0);
}

// ---------------------------------------------------------------------------
// Input dtype probe (1 = fp32 inputs).
// ---------------------------------------------------------------------------
__global__ void detect_dtype(const ushort_t* __restrict__ x, int* __restrict__ flag) {
    __shared__ int cnt;
    if (threadIdx.x == 0) cnt = 0;
    __syncthreads();
    int c = 0;
    for (int i = threadIdx.x; i < 8192; i += 256) {
        int e = (x[i] >> 7) & 0xFF;
        if (e >= 0xC8) ++c;
    }
    atomicAdd(&cnt, c);
    __syncthreads();
    if (threadIdx.x == 0) *flag = (cnt > 16) ? 1 : 0;
}

// Convert all 5 inputs (x, Wq, Wk, Wv, Wo) into one contiguous bf16 region.
#define TEN_EL ((size_t)M_ROWS * D_MODEL)
#define WEL_EL ((size_t)D_MODEL * D_MODEL)
__global__ void convert_all(const void* __restrict__ s0, const void* __restrict__ s1,
                            const void* __restrict__ s2, const void* __restrict__ s3,
                            const void* __restrict__ s4, ushort_t* __restrict__ dst,
                            const int* __restrict__ flag) {
    size_t i = ((size_t)blockIdx.x * 256 + threadIdx.x) * 8;
    const void* src;
    size_t off;
    if (i < TEN_EL) { src = s0; off = i; }
    else {
        size_t j = i - TEN_EL;
        size_t t = j >> 22;           // WEL_EL = 2^22
        src = (t == 0) ? s1 : (t == 1) ? s2 : (t == 2) ? s3 : s4;
        off = j & (WEL_EL - 1);
    }
    if (*flag) {
        const float* s = (const float*)src + off;
        union { ushort_t u[8]; float4 f; } pk;
        #pragma unroll
        for (int j = 0; j < 8; ++j) pk.u[j] = f2b(s[j]);
        *(float4*)(dst + i) = pk.f;
    } else {
        *(float4*)(dst + i) = *(const float4*)((const ushort_t*)src + off);
    }
}

// ---------------------------------------------------------------------------
// RoPE cos/sin table: tab[t*128 + i] = cos(t*invf(i)), tab[t*128+64+i] = sin.
// ---------------------------------------------------------------------------
__global__ void rope_table(float* __restrict__ tab) {
    int tid = blockIdx.x * 256 + threadIdx.x;   // t*64 + i
    int i = tid & 63, t = tid >> 6;
    float ang = (float)t * exp2f(-(float)i * 0.20762050593046015f);
    tab[t * 128 + i]      = cosf(ang);
    tab[t * 128 + 64 + i] = sinf(ang);
}

// ---------------------------------------------------------------------------
// NT GEMM, m97 structure + fused epilogues.
// mode 0: plain bf16 store (or fp32 if outf && *flag)
// mode 1: fused RoPE (table) then bf16 store       (Q/K projections)
// mode 2: store transposed to Vt (B,H,hd,T) layout (V projection)
// ---------------------------------------------------------------------------
__global__ __launch_bounds__(256) void gemm_nt(const ushort_t* __restrict__ A,
                                               const ushort_t* __restrict__ W,
                                               ushort_t* __restrict__ C,
                                               float* __restrict__ outf,
                                               const int* __restrict__ flag,
                                               const float* __restrict__ rtab,
                                               int mode, int Kdim, int Ndim) {
    __shared__ ushort_t smem[2 * 128 * 64];   // As | Ws; reused by epilogue
    ushort_t* As = smem;
    ushort_t* Ws = smem + 128 * 64;
    const int tid  = threadIdx.x;
    const int lane = tid & 63;
    const int w    = tid >> 6;
    const int wr   = (w >> 1) * 64, wc = (w & 1) * 64;
    const int quad = lane >> 4, l16 = lane & 15;
    const long bm = (long)blockIdx.y * 128;
    const long bn = (long)blockIdx.x * 128;

    f32x4 acc[4][4];
    for (int i = 0; i < 4; ++i)
        for (int j = 0; j < 4; ++j) acc[i][j] = {0.f, 0.f, 0.f, 0.f};

    const int ck0 = w * 256 + lane;
    const int sw = l16 & 7;

    for (int kb = 0; kb < Kdim; kb += 64) {
        #pragma unroll
        for (int i = 0; i < 4; ++i) {
            int ck = ck0 + i * 64;
            int r = ck >> 3, g8 = (ck & 7) ^ (r & 7);
            g2l16(A + (bm + r) * Kdim + kb + g8 * 8, As + (size_t)(w * 256 + i * 64) * 8);
            g2l16(W + (bn + r) * Kdim + kb + g8 * 8, Ws + (size_t)(w * 256 + i * 64) * 8);
        }
        __syncthreads();
        #pragma unroll
        for (int kk = 0; kk < 64; kk += 32) {
            const int gb = kk >> 3;
            bf16x8 af[4], bf[4];
            #pragma unroll
            for (int i = 0; i < 4; ++i)
                af[i] = *(const bf16x8*)(As + (wr + i * 16 + l16) * 64 + ((gb + quad) ^ sw) * 8);
            #pragma unroll
            for (int j = 0; j < 4; ++j)
                bf[j] = *(const bf16x8*)(Ws + (wc + j * 16 + l16) * 64 + ((gb + quad) ^ sw) * 8);
            #pragma unroll
            for (int i = 0; i < 4; ++i)
                #pragma unroll
                for (int j = 0; j < 4; ++j)
                    acc[i][j] = __builtin_amdgcn_mfma_f32_16x16x32_bf16(af[i], bf[j], acc[i][j], 0, 0, 0);
        }
        __syncthreads();
    }

    if (mode == 2) {
        #pragma unroll
        for (int i = 0; i < 4; ++i)
            #pragma unroll
            for (int j = 0; j < 4; ++j)
                #pragma unroll
                for (int r = 0; r < 4; ++r) {
                    int row = wr + i * 16 + quad * 4 + r;    // t within tile
                    int col = wc + j * 16 + l16;             // d within head
                    smem[col * 128 + ((((row >> 3) ^ (col & 7)) << 3) | (row & 7))] =
                        f2b(acc[i][j][r]);
                }
        __syncthreads();
        const int b = (int)(bm >> 11), t0 = (int)(bm & 2047), h = (int)(bn >> 7);
        const size_t obase = ((size_t)(b * NH + h) * HD) * T_SEQ;
        #pragma unroll
        for (int it = 0; it < 8; ++it) {
            int dd = it * 16 + (tid >> 4);
            int tch = tid & 15;
            bf16x8 v = *(const bf16x8*)(smem + dd * 128 + ((tch ^ (dd & 7)) << 3));
            *(bf16x8*)(C + obase + (size_t)dd * T_SEQ + t0 + tch * 8) = v;
        }
        return;
    }

    const int as_f32 = (outf != nullptr) && (*flag != 0);
    if (!as_f32) {
        #pragma unroll
        for (int i = 0; i < 4; ++i)
            #pragma unroll
            for (int j = 0; j < 4; ++j)
                #pragma unroll
                for (int r = 0; r < 4; ++r) {
                    int row = wr + i * 16 + quad * 4 + r;
                    int col = wc + j * 16 + l16;
                    int ch = col >> 3, off = col & 7;
                    smem[row * 128 + (((ch ^ (row & 7)) << 3) | off)] = f2b(acc[i][j][r]);
                }
        __syncthreads();
        if (mode == 1) {
            #pragma unroll
            for (int it = 0; it < 8; ++it) {
                int row = it * 16 + (tid >> 4);
                int ch  = tid & 15;
                int t = (int)((bm + row) & 2047);
                bf16x8 v = *(const bf16x8*)(smem + row * 128 + ((ch ^ (row & 7)) << 3));
                bf16x8 p = *(const bf16x8*)(smem + row * 128 + (((ch ^ 8) ^ (row & 7)) << 3));
                const float* cr = rtab + t * 128 + (ch & 7) * 8;
                float sgn = (ch < 8) ? -1.f : 1.f;
                union { ushort_t u[8]; float4 f[1]; } o;
                #pragma unroll
                for (int j = 0; j < 8; ++j) {
                    float cv = cr[j], sv = cr[64 + j];
                    o.u[j] = f2b(b2f(((const ushort_t*)&v)[j]) * cv +
                                 sgn * b2f(((const ushort_t*)&p)[j]) * sv);
                }
                *(bf16x8*)(C + (bm + row) * Ndim + bn + ch * 8) = *(const bf16x8*)o.u;
            }
        } else {
            #pragma unroll
            for (int it = 0; it < 8; ++it) {
                int row = it * 16 + (tid >> 4);
                int ch  = tid & 15;
                bf16x8 v = *(const bf16x8*)(smem + row * 128 + ((ch ^ (row & 7)) << 3));
                *(bf16x8*)(C + (bm + row) * Ndim + bn + ch * 8) = v;
            }
        }
    } else {
        float* Fs = (float*)smem;
        #pragma unroll
        for (int half = 0; half < 2; ++half) {
            __syncthreads();
            if ((w >> 1) == half) {
                #pragma unroll
                for (int i = 0; i < 4; ++i)
                    #pragma unroll
                    for (int j = 0; j < 4; ++j)
                        #pragma unroll
                        for (int r = 0; r < 4; ++r) {
                            int lr = i * 16 + quad * 4 + r;
                            int col = wc + j * 16 + l16;
                            int ch = col >> 2, off = col & 3;
                            Fs[lr * 128 + (((ch ^ (lr & 7)) << 2) | off)] = acc[i][j][r];
                        }
            }
            __syncthreads();
            #pragma unroll
            for (int it = 0; it < 8; ++it) {
                int lr = it * 8 + (tid >> 5);
                int ch = tid & 31;
                float4 v = *(const float4*)(Fs + lr * 128 + ((ch ^ (lr & 7)) << 2));
                *(float4*)(outf + (bm + half * 64 + lr) * Ndim + bn + ch * 4) = v;
            }
        }
    }
}

// ---------------------------------------------------------------------------
// Causal flash attention, fixed-M softmax (exact; see r4 analysis).
// Q-tile 128 (32 q-rows per wave, 2 groups of 16), KV-tile 64.
// Per wave-iter: 64 MFMA vs ~36 ds_read_b128 (2x work per LDS byte vs r5).
// Grid 512 EXACTLY: u=bx>>5 in [0,16), qb = u<8 ? 15-u : u-8. Dispatch pairs
// block i with i+256 on a CU -> (2(15-u)+2)+(2u+2)=34 iters/CU constant.
// LDS: Ks 16K + Vs 16K + Ps 16K = 48 KB.
// ---------------------------------------------------------------------------
#define NQT2 (T_SEQ / 128)   // 16
#define C2SM 0.1275174452f   // 128^-0.5 * log2(e)
#define MFIX 96.0f

__global__ __launch_bounds__(256, 3) void attn_kernel(const ushort_t* __restrict__ Q,
                                                      const ushort_t* __restrict__ K,
                                                      const ushort_t* __restrict__ Vt,
                                                      ushort_t* __restrict__ O) {
    __shared__ ushort_t smem[3 * 8192];
    ushort_t* Ks = smem;                 // 64 keys x 128 hd
    ushort_t* Vs = smem + 8192;          // 128 hd x 64 keys
    ushort_t* Ps = smem + 16384;         // 4 waves x 32 q x 64 keys

    const int tid = threadIdx.x;
    const int lane = tid & 63, w = tid >> 6;
    const int quad = lane >> 4, l16 = lane & 15;
    const int u = blockIdx.x >> 5;                 // [0,16)
    const int qb = (u < 8) ? (15 - u) : (u - 8);   // [0,16)
    const int bh = blockIdx.x & 31;
    const int h = bh & 15, b = bh >> 4;

    const size_t qkbase = ((size_t)(b * T_SEQ)) * D_MODEL + h * HD;
    const size_t vtbase = ((size_t)((b * NH + h) * HD)) * T_SEQ;
    const int ck0 = w * 256 + lane;
    ushort_t* Pw = Ps + w * 2048;

    // Q fragments: 2 row-groups x 4 k-slices, in registers
    bf16x8 qf[2][4];
    #pragma unroll
    for (int g = 0; g < 2; ++g) {
        const ushort_t* qrow = Q + qkbase +
            (size_t)(qb * 128 + w * 32 + g * 16 + l16) * D_MODEL;
        #pragma unroll
        for (int ks = 0; ks < 4; ++ks)
            qf[g][ks] = *(const bf16x8*)(qrow + ks * 32 + quad * 8);
    }

    float l_i[2][4] = {{0.f,0.f,0.f,0.f},{0.f,0.f,0.f,0.f}};
    f32x4 accO[2][8];
    for (int g = 0; g < 2; ++g)
        for (int i = 0; i < 8; ++i) accO[g][i] = {0.f, 0.f, 0.f, 0.f};

    const int kvmax = 2 * qb + 1;
    const int qwlo = qb * 128 + w * 32;      // lowest q row of this wave

    for (int kvb = 0; kvb <= kvmax; ++kvb) {
        __syncthreads();
        #pragma unroll
        for (int i = 0; i < 4; ++i) {
            int ck = ck0 + i * 64;
            {
                int r = ck >> 4, g = (ck & 15) ^ (r & 15);
                g2l16(K + qkbase + (size_t)(kvb * 64 + r) * D_MODEL + g * 8,
                      Ks + (size_t)(w * 256 + i * 64) * 8);
            }
            {
                int r = ck >> 3, g = (ck & 7) ^ (r & 7);
                g2l16(Vt + vtbase + (size_t)r * T_SEQ + kvb * 64 + g * 8,
                      Vs + (size_t)(w * 256 + i * 64) * 8);
            }
        }
        __syncthreads();

        if (kvb * 64 > qwlo + 31) continue;   // wave fully masked (wave-uniform)

        f32x4 accS[2][4];
        for (int g = 0; g < 2; ++g)
            for (int i = 0; i < 4; ++i) accS[g][i] = {0.f, 0.f, 0.f, 0.f};
        #pragma unroll
        for (int ks = 0; ks < 4; ++ks) {
            #pragma unroll
            for (int ct = 0; ct < 4; ++ct) {
                bf16x8 bb = *(const bf16x8*)(Ks + (ct * 16 + l16) * 128 +
                                             (((ks * 4 + quad) ^ l16) * 8));
                accS[0][ct] = __builtin_amdgcn_mfma_f32_16x16x32_bf16(qf[0][ks], bb, accS[0][ct], 0, 0, 0);
                accS[1][ct] = __builtin_amdgcn_mfma_f32_16x16x32_bf16(qf[1][ks], bb, accS[1][ct], 0, 0, 0);
            }
        }

        const int diag = (kvb * 64 + 63 > qwlo);
        #pragma unroll
        for (int g = 0; g < 2; ++g) {
            #pragma unroll
            for (int ct = 0; ct < 4; ++ct) {
                #pragma unroll
                for (int r = 0; r < 4; ++r) {
                    float pv = exp2f((accS[g][ct][r] - MFIX) * C2SM);
                    if (diag) {
                        int qg = qwlo + g * 16 + quad * 4 + r;
                        int kg = kvb * 64 + ct * 16 + l16;
                        if (kg > qg) pv = 0.f;
                    }
                    l_i[g][r] += pv;
                    int rowin = g * 16 + quad * 4 + r;
                    int col = ct * 16 + l16;
                    Pw[rowin * 64 + ((((col >> 3) ^ (rowin & 7)) << 3) | (col & 7))] = f2b(pv);
                }
            }
        }

        #pragma unroll
        for (int kk2 = 0; kk2 < 2; ++kk2) {
            bf16x8 a0 = *(const bf16x8*)(Pw + l16 * 64 +
                                         (((kk2 * 4 + quad) ^ (l16 & 7)) << 3));
            bf16x8 a1 = *(const bf16x8*)(Pw + (16 + l16) * 64 +
                                         (((kk2 * 4 + quad) ^ (l16 & 7)) << 3));
            #pragma unroll
            for (int ct = 0; ct < 8; ++ct) {
                bf16x8 bb = *(const bf16x8*)(Vs + (ct * 16 + l16) * 64 +
                                             (((kk2 * 4 + quad) ^ (l16 & 7)) * 8));
                accO[0][ct] = __builtin_amdgcn_mfma_f32_16x16x32_bf16(a0, bb, accO[0][ct], 0, 0, 0);
                accO[1][ct] = __builtin_amdgcn_mfma_f32_16x16x32_bf16(a1, bb, accO[1][ct], 0, 0, 0);
            }
        }
    }

    // l reduction within l16 group (quad-preserving), then epilogue via LDS
    float inv[2][4];
    #pragma unroll
    for (int g = 0; g < 2; ++g)
        #pragma unroll
        for (int r = 0; r < 4; ++r) {
            float v = l_i[g][r];
            for (int off = 1; off < 16; off <<= 1)
                v += __shfl_xor(v, off);
            inv[g][r] = 1.f / v;
        }

    __syncthreads();   // all waves done reading Ks/Vs
    #pragma unroll
    for (int g = 0; g < 2; ++g)
        #pragma unroll
        for (int ct = 0; ct < 8; ++ct)
            #pragma unroll
            for (int r = 0; r < 4; ++r) {
                int row = w * 32 + g * 16 + quad * 4 + r;     // 0..127
                int col = ct * 16 + l16;                      // 0..127
                smem[row * 128 + ((((col >> 3) ^ (row & 7)) << 3) | (col & 7))] =
                    f2b(accO[g][ct][r] * inv[g][r]);
            }
    __syncthreads();
    #pragma unroll
    for (int it = 0; it < 8; ++it) {
        int row = it * 16 + (tid >> 4);
        int ch  = tid & 15;
        bf16x8 v = *(const bf16x8*)(smem + row * 128 + ((ch ^ (row & 7)) << 3));
        *(bf16x8*)(O + ((size_t)(b * T_SEQ + qb * 128 + row)) * D_MODEL + h * HD + ch * 8) = v;
    }
}

// ---------------------------------------------------------------------------
extern "C" void kernel_launch(void* const* d_in, const int* in_sizes, int n_in,
                              void* d_out, int out_size, void* d_ws, size_t ws_size,
                              hipStream_t stream) {
    const size_t TEN = TEN_EL;
    const size_t WEL = WEL_EL;

    char* ws = (char*)d_ws;
    int* flag = (int*)ws;
    ushort_t* xb  = (ushort_t*)(ws + 256);
    ushort_t* Wqb = xb  + TEN;
    ushort_t* Wkb = Wqb + WEL;
    ushort_t* Wvb = Wkb + WEL;
    ushort_t* Wob = Wvb + WEL;
    ushort_t* Qb  = Wob + WEL;
    ushort_t* Kb  = Qb + TEN;
    ushort_t* attn = Kb + TEN;
    ushort_t* Vt  = attn + TEN;
    float* rtab = (float*)(Vt + TEN); // 2048*128 floats = 1 MB

    detect_dtype<<<1, 256, 0, stream>>>((const ushort_t*)d_in[0], flag);
    rope_table<<<(T_SEQ * 64) / 256, 256, 0, stream>>>(rtab);
    {
        size_t tot = TEN + 4 * WEL;            // 25,165,824 elements
        convert_all<<<(int)(tot / 8 / 256), 256, 0, stream>>>(
            d_in[0], d_in[1], d_in[2], d_in[3], d_in[4], xb, flag);
    }

    dim3 gg(D_MODEL / 128, M_ROWS / 128);
    gemm_nt<<<gg, 256, 0, stream>>>(xb, Wqb, Qb, nullptr, flag, rtab, 1, D_MODEL, D_MODEL);
    gemm_nt<<<gg, 256, 0, stream>>>(xb, Wkb, Kb, nullptr, flag, rtab, 1, D_MODEL, D_MODEL);
    gemm_nt<<<gg, 256, 0, stream>>>(xb, Wvb, Vt, nullptr, flag, rtab, 2, D_MODEL, D_MODEL);
    attn_kernel<<<dim3(NQT2 * NB * NH), 256, 0, stream>>>(Qb, Kb, Vt, attn);
    gemm_nt<<<gg, 256, 0, stream>>>(attn, Wob, (ushort_t*)d_out, (float*)d_out, flag,
                                    rtab, 0, D_MODEL, D_MODEL);
}